// Round 2
// baseline (166.349 us; speedup 1.0000x reference)
//
#include <hip/hip_runtime.h>

// out[i] = gen_map[x_gen[i]] + c * x_max_clock_speed[i] + d * x_max_tdp[i]
// N = 8388608 (2^23), NUM_GENS = 1024.
// Memory-bound: 16 B/elem mandatory -> 134 MB -> ~21 us at 6.3 TB/s.
// R1 was latency-bound (45 us, 2.9 TB/s effective): 8192 single-shot blocks,
// per-block staging+barrier prologue dominated. R2: persistent grid-stride,
// 2048 blocks (8/CU -> 32 waves/CU), 4 vec4 groups per thread with all 12
// dwordx4 loads issued before first use (deep MLP), float4 LDS staging.

#define NUM_GENS 1024
#define BLOCK 256
#define GRID 2048
#define UNROLL 4

__global__ __launch_bounds__(BLOCK)
void Model_64364379898151_kernel(const int* __restrict__ x_gen,
                                 const float* __restrict__ x_clock,
                                 const float* __restrict__ x_tdp,
                                 const float* __restrict__ gen_map,
                                 const float* __restrict__ c_ptr,
                                 const float* __restrict__ d_ptr,
                                 float* __restrict__ out,
                                 int n_vec)  // number of vec4 groups
{
    __shared__ float s_map[NUM_GENS];
    // 256 threads x float4 = 1024 floats, one ds_write_b128 each.
    ((float4*)s_map)[threadIdx.x] = ((const float4*)gen_map)[threadIdx.x];
    __syncthreads();

    const float c = c_ptr[0];
    const float d = d_ptr[0];

    const int stride = GRID * BLOCK;             // 524288 vec4 groups
    int idx = blockIdx.x * BLOCK + threadIdx.x;

    const int4*   g4 = (const int4*)  x_gen;
    const float4* c4 = (const float4*)x_clock;
    const float4* t4 = (const float4*)x_tdp;
    float4*       o4 = (float4*)      out;

    for (int base = idx; base < n_vec; base += UNROLL * stride) {
        const int i1 = base + stride;
        const int i2 = base + 2 * stride;
        const int i3 = base + 3 * stride;

        if (i3 < n_vec) {
            // Fast path: issue all 12 loads, then compute. (For N=2^23 this
            // is the only path: n_vec/stride == 4 exactly.)
            int4   g0 = g4[base], g1 = g4[i1], g2 = g4[i2], g3 = g4[i3];
            float4 cs0 = c4[base], cs1 = c4[i1], cs2 = c4[i2], cs3 = c4[i3];
            float4 td0 = t4[base], td1 = t4[i1], td2 = t4[i2], td3 = t4[i3];

            float4 o0, o1, o2, o3;
            o0.x = s_map[g0.x] + c * cs0.x + d * td0.x;
            o0.y = s_map[g0.y] + c * cs0.y + d * td0.y;
            o0.z = s_map[g0.z] + c * cs0.z + d * td0.z;
            o0.w = s_map[g0.w] + c * cs0.w + d * td0.w;
            o1.x = s_map[g1.x] + c * cs1.x + d * td1.x;
            o1.y = s_map[g1.y] + c * cs1.y + d * td1.y;
            o1.z = s_map[g1.z] + c * cs1.z + d * td1.z;
            o1.w = s_map[g1.w] + c * cs1.w + d * td1.w;
            o2.x = s_map[g2.x] + c * cs2.x + d * td2.x;
            o2.y = s_map[g2.y] + c * cs2.y + d * td2.y;
            o2.z = s_map[g2.z] + c * cs2.z + d * td2.z;
            o2.w = s_map[g2.w] + c * cs2.w + d * td2.w;
            o3.x = s_map[g3.x] + c * cs3.x + d * td3.x;
            o3.y = s_map[g3.y] + c * cs3.y + d * td3.y;
            o3.z = s_map[g3.z] + c * cs3.z + d * td3.z;
            o3.w = s_map[g3.w] + c * cs3.w + d * td3.w;

            o4[base] = o0; o4[i1] = o1; o4[i2] = o2; o4[i3] = o3;
        } else {
            // Tail path (not taken for N=2^23, kept for generality).
            for (int k = 0; k < UNROLL; ++k) {
                int i = base + k * stride;
                if (i < n_vec) {
                    int4   g  = g4[i];
                    float4 cs = c4[i];
                    float4 td = t4[i];
                    float4 o;
                    o.x = s_map[g.x] + c * cs.x + d * td.x;
                    o.y = s_map[g.y] + c * cs.y + d * td.y;
                    o.z = s_map[g.z] + c * cs.z + d * td.z;
                    o.w = s_map[g.w] + c * cs.w + d * td.w;
                    o4[i] = o;
                }
            }
        }
    }
}

extern "C" void kernel_launch(void* const* d_in, const int* in_sizes, int n_in,
                              void* d_out, int out_size, void* d_ws, size_t ws_size,
                              hipStream_t stream) {
    // setup_inputs() order:
    // 0: x_gen (int32, N)         1: x_ix (int32, N) -- unused
    // 2: x_max_clock_speed (f32)  3: x_max_tdp (f32)
    // 4: gen_map (f32, 1024)
    // 5: b (f32 scalar, unused)   6: c (f32 scalar)   7: d (f32 scalar)
    const int*   x_gen   = (const int*)  d_in[0];
    const float* x_clock = (const float*)d_in[2];
    const float* x_tdp   = (const float*)d_in[3];
    const float* gen_map = (const float*)d_in[4];
    const float* c_ptr   = (const float*)d_in[6];
    const float* d_ptr   = (const float*)d_in[7];
    float* out = (float*)d_out;

    const int n = in_sizes[0];          // 8388608
    const int n_vec = n / 4;            // 2^21 vec4 groups

    Model_64364379898151_kernel<<<GRID, BLOCK, 0, stream>>>(
        x_gen, x_clock, x_tdp, gen_map, c_ptr, d_ptr, out, n_vec);
}

// Round 4
// 162.205 us; speedup vs baseline: 1.0256x; 1.0256x over previous
//
#include <hip/hip_runtime.h>

// out[i] = gen_map[x_gen[i]] + c * x_max_clock_speed[i] + d * x_max_tdp[i]
// N = 8388608 (2^23), NUM_GENS = 1024.
// Mandatory traffic 16 B/elem = 134 MB -> ~21 us at 6.3 TB/s.
// R1 (single-shot, LDS gather): 45 us. R2 (persistent, 12-deep MLP, LDS
// gather): 44 us — identical. MLP/structure is not the limiter.
// R3/R4: no LDS + no barrier (gen_map gathered via L1; 4 KB = 32 lines,
// L1-resident per CU), nontemporal stores (write-once stream, no-allocate
// keeps input lines in L2). R3 failed to compile: nontemporal builtin
// rejects HIP_vector_type; R4 uses native ext_vector_type for the store.

#define BLOCK 256
#define GRID 2048
#define UNROLL 4

typedef float nfloat4 __attribute__((ext_vector_type(4)));

__device__ __forceinline__ void nt_store4(float4 v, float4* p) {
    nfloat4 nv = {v.x, v.y, v.z, v.w};
    __builtin_nontemporal_store(nv, (nfloat4*)p);
}

__global__ __launch_bounds__(BLOCK)
void Model_64364379898151_kernel(const int* __restrict__ x_gen,
                                 const float* __restrict__ x_clock,
                                 const float* __restrict__ x_tdp,
                                 const float* __restrict__ gen_map,
                                 const float* __restrict__ c_ptr,
                                 const float* __restrict__ d_ptr,
                                 float* __restrict__ out,
                                 int n_vec)  // number of vec4 groups
{
    const float c = c_ptr[0];
    const float d = d_ptr[0];

    const int stride = GRID * BLOCK;            // 524288 vec4 groups
    const int idx = blockIdx.x * BLOCK + threadIdx.x;

    const int4*   g4 = (const int4*)  x_gen;
    const float4* c4 = (const float4*)x_clock;
    const float4* t4 = (const float4*)x_tdp;
    float4*       o4 = (float4*)      out;

    for (int base = idx; base < n_vec; base += UNROLL * stride) {
        const int i1 = base + stride;
        const int i2 = base + 2 * stride;
        const int i3 = base + 3 * stride;

        if (i3 < n_vec) {
            // Only path for N = 2^23 (n_vec == UNROLL * stride exactly).
            int4   g0 = g4[base], g1 = g4[i1], g2 = g4[i2], g3 = g4[i3];
            float4 a0 = c4[base], a1 = c4[i1], a2 = c4[i2], a3 = c4[i3];
            float4 b0 = t4[base], b1 = t4[i1], b2 = t4[i2], b3 = t4[i3];

            float4 o0, o1, o2, o3;
            o0.x = gen_map[g0.x] + c * a0.x + d * b0.x;
            o0.y = gen_map[g0.y] + c * a0.y + d * b0.y;
            o0.z = gen_map[g0.z] + c * a0.z + d * b0.z;
            o0.w = gen_map[g0.w] + c * a0.w + d * b0.w;
            o1.x = gen_map[g1.x] + c * a1.x + d * b1.x;
            o1.y = gen_map[g1.y] + c * a1.y + d * b1.y;
            o1.z = gen_map[g1.z] + c * a1.z + d * b1.z;
            o1.w = gen_map[g1.w] + c * a1.w + d * b1.w;
            o2.x = gen_map[g2.x] + c * a2.x + d * b2.x;
            o2.y = gen_map[g2.y] + c * a2.y + d * b2.y;
            o2.z = gen_map[g2.z] + c * a2.z + d * b2.z;
            o2.w = gen_map[g2.w] + c * a2.w + d * b2.w;
            o3.x = gen_map[g3.x] + c * a3.x + d * b3.x;
            o3.y = gen_map[g3.y] + c * a3.y + d * b3.y;
            o3.z = gen_map[g3.z] + c * a3.z + d * b3.z;
            o3.w = gen_map[g3.w] + c * a3.w + d * b3.w;

            nt_store4(o0, &o4[base]);
            nt_store4(o1, &o4[i1]);
            nt_store4(o2, &o4[i2]);
            nt_store4(o3, &o4[i3]);
        } else {
            // Tail (not taken for N = 2^23).
            for (int k = 0; k < UNROLL; ++k) {
                int i = base + k * stride;
                if (i < n_vec) {
                    int4   g  = g4[i];
                    float4 cs = c4[i];
                    float4 td = t4[i];
                    float4 o;
                    o.x = gen_map[g.x] + c * cs.x + d * td.x;
                    o.y = gen_map[g.y] + c * cs.y + d * td.y;
                    o.z = gen_map[g.z] + c * cs.z + d * td.z;
                    o.w = gen_map[g.w] + c * cs.w + d * td.w;
                    nt_store4(o, &o4[i]);
                }
            }
        }
    }
}

extern "C" void kernel_launch(void* const* d_in, const int* in_sizes, int n_in,
                              void* d_out, int out_size, void* d_ws, size_t ws_size,
                              hipStream_t stream) {
    // setup_inputs() order:
    // 0: x_gen (int32, N)         1: x_ix (int32, N) -- unused
    // 2: x_max_clock_speed (f32)  3: x_max_tdp (f32)
    // 4: gen_map (f32, 1024)
    // 5: b (f32 scalar, unused)   6: c (f32 scalar)   7: d (f32 scalar)
    const int*   x_gen   = (const int*)  d_in[0];
    const float* x_clock = (const float*)d_in[2];
    const float* x_tdp   = (const float*)d_in[3];
    const float* gen_map = (const float*)d_in[4];
    const float* c_ptr   = (const float*)d_in[6];
    const float* d_ptr   = (const float*)d_in[7];
    float* out = (float*)d_out;

    const int n = in_sizes[0];          // 8388608
    const int n_vec = n / 4;            // 2^21 vec4 groups

    Model_64364379898151_kernel<<<GRID, BLOCK, 0, stream>>>(
        x_gen, x_clock, x_tdp, gen_map, c_ptr, d_ptr, out, n_vec);
}

// Round 5
// 158.206 us; speedup vs baseline: 1.0515x; 1.0253x over previous
//
#include <hip/hip_runtime.h>

// out[i] = gen_map[x_gen[i]] + c * x_max_clock_speed[i] + d * x_max_tdp[i]
// N = 8388608 (2^23), NUM_GENS = 1024.
// Mandatory traffic 16 B/elem = 134 MB -> ~21 us at 6.3 TB/s ceiling.
// History: R1 (single-shot, LDS gather) 45 us; R2 (persistent, MLP, LDS
// gather) 44 us; R4 (persistent, L1 gather, nt stores) 42 us. All pinned at
// ~2 TB/s effective with every pipe counter (HBM, VALU, LDS-conflict, occ)
// far from its limit. Remaining suspect: TA/L1 contention between the
// random per-lane gather and 129 MB of streaming traffic.
// R5: gather via LDS (off the TA), streams via nontemporal loads (off the
// L1-allocate path), nt stores, launch_bounds(256,4) so all 12 stream loads
// stay in flight (R2/R4 got squeezed to 32-36 VGPRs and serialized).

#define NUM_GENS 1024
#define BLOCK 256
#define GRID 2048
#define UNROLL 4

typedef float nfloat4 __attribute__((ext_vector_type(4)));
typedef int   nint4   __attribute__((ext_vector_type(4)));

__global__ __launch_bounds__(BLOCK, 4)
void Model_64364379898151_kernel(const int* __restrict__ x_gen,
                                 const float* __restrict__ x_clock,
                                 const float* __restrict__ x_tdp,
                                 const float* __restrict__ gen_map,
                                 const float* __restrict__ c_ptr,
                                 const float* __restrict__ d_ptr,
                                 float* __restrict__ out,
                                 int n_vec)  // number of vec4 groups
{
    __shared__ float s_map[NUM_GENS];
    ((float4*)s_map)[threadIdx.x] = ((const float4*)gen_map)[threadIdx.x];
    __syncthreads();

    const float c = c_ptr[0];
    const float d = d_ptr[0];

    const int stride = GRID * BLOCK;            // 524288 vec4 groups
    const int idx = blockIdx.x * BLOCK + threadIdx.x;

    const nint4*   g4 = (const nint4*)  x_gen;
    const nfloat4* c4 = (const nfloat4*)x_clock;
    const nfloat4* t4 = (const nfloat4*)x_tdp;
    nfloat4*       o4 = (nfloat4*)      out;

    for (int base = idx; base < n_vec; base += UNROLL * stride) {
        const int i1 = base + stride;
        const int i2 = base + 2 * stride;
        const int i3 = base + 3 * stride;

        if (i3 < n_vec) {
            // Only path for N = 2^23 (n_vec == UNROLL * stride exactly).
            // Issue all 12 streaming loads (nt: no L1/L2 allocate) first.
            nint4   g0 = __builtin_nontemporal_load(g4 + base);
            nint4   g1 = __builtin_nontemporal_load(g4 + i1);
            nint4   g2 = __builtin_nontemporal_load(g4 + i2);
            nint4   g3 = __builtin_nontemporal_load(g4 + i3);
            nfloat4 a0 = __builtin_nontemporal_load(c4 + base);
            nfloat4 a1 = __builtin_nontemporal_load(c4 + i1);
            nfloat4 a2 = __builtin_nontemporal_load(c4 + i2);
            nfloat4 a3 = __builtin_nontemporal_load(c4 + i3);
            nfloat4 b0 = __builtin_nontemporal_load(t4 + base);
            nfloat4 b1 = __builtin_nontemporal_load(t4 + i1);
            nfloat4 b2 = __builtin_nontemporal_load(t4 + i2);
            nfloat4 b3 = __builtin_nontemporal_load(t4 + i3);

            nfloat4 o0, o1, o2, o3;
            o0.x = s_map[g0.x] + c * a0.x + d * b0.x;
            o0.y = s_map[g0.y] + c * a0.y + d * b0.y;
            o0.z = s_map[g0.z] + c * a0.z + d * b0.z;
            o0.w = s_map[g0.w] + c * a0.w + d * b0.w;
            o1.x = s_map[g1.x] + c * a1.x + d * b1.x;
            o1.y = s_map[g1.y] + c * a1.y + d * b1.y;
            o1.z = s_map[g1.z] + c * a1.z + d * b1.z;
            o1.w = s_map[g1.w] + c * a1.w + d * b1.w;
            o2.x = s_map[g2.x] + c * a2.x + d * b2.x;
            o2.y = s_map[g2.y] + c * a2.y + d * b2.y;
            o2.z = s_map[g2.z] + c * a2.z + d * b2.z;
            o2.w = s_map[g2.w] + c * a2.w + d * b2.w;
            o3.x = s_map[g3.x] + c * a3.x + d * b3.x;
            o3.y = s_map[g3.y] + c * a3.y + d * b3.y;
            o3.z = s_map[g3.z] + c * a3.z + d * b3.z;
            o3.w = s_map[g3.w] + c * a3.w + d * b3.w;

            __builtin_nontemporal_store(o0, o4 + base);
            __builtin_nontemporal_store(o1, o4 + i1);
            __builtin_nontemporal_store(o2, o4 + i2);
            __builtin_nontemporal_store(o3, o4 + i3);
        } else {
            // Tail (not taken for N = 2^23).
            for (int k = 0; k < UNROLL; ++k) {
                int i = base + k * stride;
                if (i < n_vec) {
                    nint4   g  = __builtin_nontemporal_load(g4 + i);
                    nfloat4 cs = __builtin_nontemporal_load(c4 + i);
                    nfloat4 td = __builtin_nontemporal_load(t4 + i);
                    nfloat4 o;
                    o.x = s_map[g.x] + c * cs.x + d * td.x;
                    o.y = s_map[g.y] + c * cs.y + d * td.y;
                    o.z = s_map[g.z] + c * cs.z + d * td.z;
                    o.w = s_map[g.w] + c * cs.w + d * td.w;
                    __builtin_nontemporal_store(o, o4 + i);
                }
            }
        }
    }
}

extern "C" void kernel_launch(void* const* d_in, const int* in_sizes, int n_in,
                              void* d_out, int out_size, void* d_ws, size_t ws_size,
                              hipStream_t stream) {
    // setup_inputs() order:
    // 0: x_gen (int32, N)         1: x_ix (int32, N) -- unused
    // 2: x_max_clock_speed (f32)  3: x_max_tdp (f32)
    // 4: gen_map (f32, 1024)
    // 5: b (f32 scalar, unused)   6: c (f32 scalar)   7: d (f32 scalar)
    const int*   x_gen   = (const int*)  d_in[0];
    const float* x_clock = (const float*)d_in[2];
    const float* x_tdp   = (const float*)d_in[3];
    const float* gen_map = (const float*)d_in[4];
    const float* c_ptr   = (const float*)d_in[6];
    const float* d_ptr   = (const float*)d_in[7];
    float* out = (float*)d_out;

    const int n = in_sizes[0];          // 8388608
    const int n_vec = n / 4;            // 2^21 vec4 groups

    Model_64364379898151_kernel<<<GRID, BLOCK, 0, stream>>>(
        x_gen, x_clock, x_tdp, gen_map, c_ptr, d_ptr, out, n_vec);
}

// Round 6
// 157.383 us; speedup vs baseline: 1.0570x; 1.0052x over previous
//
#include <hip/hip_runtime.h>

// out[i] = gen_map[x_gen[i]] + c * x_max_clock_speed[i] + d * x_max_tdp[i]
// N = 8388608 (2^23), NUM_GENS = 1024.
// Mandatory logical traffic 16 B/elem = 134 MB; harness's 268 MB ws-poison
// fill thrashes L3 between restore and kernel, so ~49 MB of reads are
// HBM-mandatory -> HBM-side floor ~82 MB ~ 13 us; realistic ~20-24 us.
// History: R1 45us / R2 44us / R4 42us / R5 ~38us (LDS gather + nt loads +
// nt stores). R5's "loop" ran exactly once per thread: load-burst ->
// dep-chain -> store-burst -> retire, no intra-wave pipelining, and the
// compiler kept only ~3 loads in flight (32-36 VGPR).
// R6: GRID 1024 -> each thread owns TWO stages; issue both stages' 24 nt
// loads up front (explicit SW pipeline), launch_bounds(256,4) = 128 VGPR
// cap so they can actually stay in flight.

#define NUM_GENS 1024
#define BLOCK 256
#define GRID 1024
#define UNROLL 4

typedef float nfloat4 __attribute__((ext_vector_type(4)));
typedef int   nint4   __attribute__((ext_vector_type(4)));

__device__ __forceinline__ nfloat4 stage_compute(const float* s_map, float c, float d,
                                                 nint4 g, nfloat4 a, nfloat4 b) {
    nfloat4 o;
    o.x = s_map[g.x] + c * a.x + d * b.x;
    o.y = s_map[g.y] + c * a.y + d * b.y;
    o.z = s_map[g.z] + c * a.z + d * b.z;
    o.w = s_map[g.w] + c * a.w + d * b.w;
    return o;
}

__global__ __launch_bounds__(BLOCK, 4)
void Model_64364379898151_kernel(const int* __restrict__ x_gen,
                                 const float* __restrict__ x_clock,
                                 const float* __restrict__ x_tdp,
                                 const float* __restrict__ gen_map,
                                 const float* __restrict__ c_ptr,
                                 const float* __restrict__ d_ptr,
                                 float* __restrict__ out,
                                 int n_vec)  // number of vec4 groups
{
    __shared__ float s_map[NUM_GENS];
    ((float4*)s_map)[threadIdx.x] = ((const float4*)gen_map)[threadIdx.x];
    __syncthreads();

    const float c = c_ptr[0];
    const float d = d_ptr[0];

    const int stride = GRID * BLOCK;            // 262144 vec4 groups
    const int idx = blockIdx.x * BLOCK + threadIdx.x;

    const nint4*   g4 = (const nint4*)  x_gen;
    const nfloat4* c4 = (const nfloat4*)x_clock;
    const nfloat4* t4 = (const nfloat4*)x_tdp;
    nfloat4*       o4 = (nfloat4*)      out;

    if (n_vec == 8 * stride) {
        // Fast path for N = 2^23: exactly 8 vec4 groups per thread,
        // two 4-group stages, all 24 loads issued before any use.
        const int j0 = idx;
        const int j1 = idx + 1 * stride;
        const int j2 = idx + 2 * stride;
        const int j3 = idx + 3 * stride;
        const int j4 = idx + 4 * stride;
        const int j5 = idx + 5 * stride;
        const int j6 = idx + 6 * stride;
        const int j7 = idx + 7 * stride;

        // Stage A loads
        nint4   gA0 = __builtin_nontemporal_load(g4 + j0);
        nint4   gA1 = __builtin_nontemporal_load(g4 + j1);
        nint4   gA2 = __builtin_nontemporal_load(g4 + j2);
        nint4   gA3 = __builtin_nontemporal_load(g4 + j3);
        nfloat4 aA0 = __builtin_nontemporal_load(c4 + j0);
        nfloat4 aA1 = __builtin_nontemporal_load(c4 + j1);
        nfloat4 aA2 = __builtin_nontemporal_load(c4 + j2);
        nfloat4 aA3 = __builtin_nontemporal_load(c4 + j3);
        nfloat4 bA0 = __builtin_nontemporal_load(t4 + j0);
        nfloat4 bA1 = __builtin_nontemporal_load(t4 + j1);
        nfloat4 bA2 = __builtin_nontemporal_load(t4 + j2);
        nfloat4 bA3 = __builtin_nontemporal_load(t4 + j3);
        // Stage B loads (issued before stage A is consumed)
        nint4   gB0 = __builtin_nontemporal_load(g4 + j4);
        nint4   gB1 = __builtin_nontemporal_load(g4 + j5);
        nint4   gB2 = __builtin_nontemporal_load(g4 + j6);
        nint4   gB3 = __builtin_nontemporal_load(g4 + j7);
        nfloat4 aB0 = __builtin_nontemporal_load(c4 + j4);
        nfloat4 aB1 = __builtin_nontemporal_load(c4 + j5);
        nfloat4 aB2 = __builtin_nontemporal_load(c4 + j6);
        nfloat4 aB3 = __builtin_nontemporal_load(c4 + j7);
        nfloat4 bB0 = __builtin_nontemporal_load(t4 + j4);
        nfloat4 bB1 = __builtin_nontemporal_load(t4 + j5);
        nfloat4 bB2 = __builtin_nontemporal_load(t4 + j6);
        nfloat4 bB3 = __builtin_nontemporal_load(t4 + j7);

        // Consume stage A while stage B is still in flight.
        __builtin_nontemporal_store(stage_compute(s_map, c, d, gA0, aA0, bA0), o4 + j0);
        __builtin_nontemporal_store(stage_compute(s_map, c, d, gA1, aA1, bA1), o4 + j1);
        __builtin_nontemporal_store(stage_compute(s_map, c, d, gA2, aA2, bA2), o4 + j2);
        __builtin_nontemporal_store(stage_compute(s_map, c, d, gA3, aA3, bA3), o4 + j3);
        // Stage B
        __builtin_nontemporal_store(stage_compute(s_map, c, d, gB0, aB0, bB0), o4 + j4);
        __builtin_nontemporal_store(stage_compute(s_map, c, d, gB1, aB1, bB1), o4 + j5);
        __builtin_nontemporal_store(stage_compute(s_map, c, d, gB2, aB2, bB2), o4 + j6);
        __builtin_nontemporal_store(stage_compute(s_map, c, d, gB3, aB3, bB3), o4 + j7);
    } else {
        // Generic grid-stride fallback (not taken for N = 2^23).
        for (int i = idx; i < n_vec; i += stride) {
            nint4   g  = __builtin_nontemporal_load(g4 + i);
            nfloat4 cs = __builtin_nontemporal_load(c4 + i);
            nfloat4 td = __builtin_nontemporal_load(t4 + i);
            __builtin_nontemporal_store(stage_compute(s_map, c, d, g, cs, td), o4 + i);
        }
    }
}

extern "C" void kernel_launch(void* const* d_in, const int* in_sizes, int n_in,
                              void* d_out, int out_size, void* d_ws, size_t ws_size,
                              hipStream_t stream) {
    // setup_inputs() order:
    // 0: x_gen (int32, N)         1: x_ix (int32, N) -- unused
    // 2: x_max_clock_speed (f32)  3: x_max_tdp (f32)
    // 4: gen_map (f32, 1024)
    // 5: b (f32 scalar, unused)   6: c (f32 scalar)   7: d (f32 scalar)
    const int*   x_gen   = (const int*)  d_in[0];
    const float* x_clock = (const float*)d_in[2];
    const float* x_tdp   = (const float*)d_in[3];
    const float* gen_map = (const float*)d_in[4];
    const float* c_ptr   = (const float*)d_in[6];
    const float* d_ptr   = (const float*)d_in[7];
    float* out = (float*)d_out;

    const int n = in_sizes[0];          // 8388608
    const int n_vec = n / 4;            // 2^21 vec4 groups

    Model_64364379898151_kernel<<<GRID, BLOCK, 0, stream>>>(
        x_gen, x_clock, x_tdp, gen_map, c_ptr, d_ptr, out, n_vec);
}